// Round 3
// baseline (562.661 us; speedup 1.0000x reference)
//
#include <hip/hip_runtime.h>
#include <hip/hip_bf16.h>

#define NANCH 202500
#define PRE_NMS 6000
#define POST_NMS 300
#define KW 94            // ceil(6016/64)
#define CAP 8192
#define SORT_SZ 8192
#define NBUCK 16384
#define BSHIFT 18
#define IOU_TH 0.7f
#define MIN_SIZE 0.016f
#define TB_PAD 6016      // topbox padded to a multiple of 64

typedef unsigned long long ull;

// ---------------- shared decode / key helpers ---------------------------
__device__ inline float4 decode_box(const float* __restrict__ loc,
                                    const float* __restrict__ anc, int i) {
    float4 a = ((const float4*)anc)[i];
    float4 t = ((const float4*)loc)[i];
    float pw = a.z - a.x, ph = a.w - a.y;
    float pcx = (a.x + a.z) * 0.5f, pcy = (a.y + a.w) * 0.5f;
    float cx = t.x * pw + pcx, cy = t.y * ph + pcy;
    float w = expf(t.z) * pw, h = expf(t.w) * ph;
    float x1 = fminf(fmaxf(cx - 0.5f * w, 0.f), 1.f);
    float y1 = fminf(fmaxf(cy - 0.5f * h, 0.f), 1.f);
    float x2 = fminf(fmaxf(cx + 0.5f * w, 0.f), 1.f);
    float y2 = fminf(fmaxf(cy + 0.5f * h, 0.f), 1.f);
    return make_float4(x1, y1, x2, y2);
}

__device__ inline unsigned make_key(const float* __restrict__ cls,
                                    const float* __restrict__ loc,
                                    const float* __restrict__ anc, int i) {
    float2 c = ((const float2*)cls)[i];
    float d = c.y - c.x;                       // monotone proxy for softmax[:,1]
    float4 b = decode_box(loc, anc, i);
    bool valid = ((b.z - b.x) >= MIN_SIZE) && ((b.w - b.y) >= MIN_SIZE);
    unsigned ib = __float_as_uint(d);
    unsigned u = (ib & 0x80000000u) ? ~ib : (ib | 0x80000000u);  // monotonic key
    return valid ? u : 0u;                     // invalid -> below everything
}

// ---------------- K1: histogram (+ optional key cache) -------------------
__global__ __launch_bounds__(256) void k_score(const float* __restrict__ cls,
                                               const float* __restrict__ loc,
                                               const float* __restrict__ anc,
                                               unsigned* __restrict__ hist,
                                               unsigned* __restrict__ keyc, int n) {
    int i = blockIdx.x * blockDim.x + threadIdx.x;
    if (i >= n) return;
    unsigned u = make_key(cls, loc, anc, i);
    if (keyc) keyc[i] = u;
    atomicAdd(&hist[u >> BSHIFT], 1u);
}

// ---------------- K2: find boundary bucket B (rank 6000 from top) -------
__global__ __launch_bounds__(1024) void k_findb(const unsigned* __restrict__ hist,
                                                unsigned* __restrict__ meta) {
    __shared__ unsigned ps[1024];
    int t = threadIdx.x;
    int base = t * (NBUCK / 1024);
    unsigned local = 0;
    for (int b = 0; b < NBUCK / 1024; b++) local += hist[base + b];
    ps[t] = local;
    __syncthreads();
    for (int off = 1; off < 1024; off <<= 1) {
        unsigned add = (t + off < 1024) ? ps[t + off] : 0u;
        __syncthreads();
        ps[t] += add;
        __syncthreads();
    }
    unsigned incl = ps[t];
    unsigned excl = incl - local;
    if (incl >= (unsigned)PRE_NMS && excl < (unsigned)PRE_NMS) {
        unsigned cum = excl;
        int B = base;
        for (int b = NBUCK / 1024 - 1; b >= 0; b--) {
            cum += hist[base + b];
            if (cum >= (unsigned)PRE_NMS) { B = base + b; break; }
        }
        meta[0] = (unsigned)B;
    }
}

// ---------------- K3a: compact from cached keys --------------------------
__global__ __launch_bounds__(256) void k_compactC(const unsigned* __restrict__ keyc,
                                                  unsigned* __restrict__ meta,
                                                  ull* __restrict__ cand, int n) {
    int i = blockIdx.x * blockDim.x + threadIdx.x;
    if (i >= n) return;
    unsigned u = keyc[i];
    if ((u >> BSHIFT) >= meta[0]) {
        unsigned p = atomicAdd(&meta[1], 1u);
        if (p < CAP)
            cand[p] = ((ull)(~u) << 32) | (unsigned)i;   // asc = score desc, idx asc
    }
}

// ---------------- K3b: compact, recompute keys (small-ws fallback) ------
__global__ __launch_bounds__(256) void k_compactR(const float* __restrict__ cls,
                                                  const float* __restrict__ loc,
                                                  const float* __restrict__ anc,
                                                  unsigned* __restrict__ meta,
                                                  ull* __restrict__ cand, int n) {
    int i = blockIdx.x * blockDim.x + threadIdx.x;
    if (i >= n) return;
    unsigned u = make_key(cls, loc, anc, i);
    if ((u >> BSHIFT) >= meta[0]) {
        unsigned p = atomicAdd(&meta[1], 1u);
        if (p < CAP)
            cand[p] = ((ull)(~u) << 32) | (unsigned)i;
    }
}

// ---------------- K4: bitonic sort 8192 (wave-segment, few barriers) ----
// Wave w owns elements [512w, 512w+512). Passes with j<512 stay inside one
// wave's segment: LDS ops of a single wave complete in issue order, so no
// barrier is needed. Only j>=512 passes (and the first pass after them)
// require __syncthreads -> ~15 barriers instead of 91.
__global__ __launch_bounds__(1024) void k_sort(const ull* __restrict__ cand,
                                               const unsigned* __restrict__ meta,
                                               const float* __restrict__ loc,
                                               const float* __restrict__ anc,
                                               float4* __restrict__ topbox,
                                               ull* __restrict__ vmask) {
    __shared__ ull sk[SORT_SZ];   // 64 KB
    int tid = threadIdx.x;
    int wv = tid >> 6, l = tid & 63;
    int base = wv * 512;
    unsigned C = meta[1];
    if (C > CAP) C = CAP;
    #pragma unroll
    for (int m = 0; m < 8; m++) {
        int i = base + m * 64 + l;
        sk[i] = (i < (int)C) ? cand[i] : ~0ull;
    }
    bool prev = false;
    for (int k = 2; k <= SORT_SZ; k <<= 1) {
        for (int j = k >> 1; j > 0; j >>= 1) {
            bool cross = (j >= 512);
            if (cross || prev) __syncthreads();
            prev = cross;
            #pragma unroll
            for (int m = 0; m < 8; m++) {
                int i = base + m * 64 + l;
                int ixj = i ^ j;
                if (ixj > i) {
                    bool up = ((i & k) == 0);
                    ull A = sk[i], B = sk[ixj];
                    if ((up && A > B) || (!up && A < B)) { sk[i] = B; sk[ixj] = A; }
                }
            }
        }
    }
    __syncthreads();
    for (int q = tid; q < TB_PAD; q += 1024) {
        ull kv = sk[q];
        unsigned uu = ~(unsigned)(kv >> 32);
        int idx = (int)(unsigned)kv;
        bool val = (q < PRE_NMS) && (uu != 0u);
        topbox[q] = val ? decode_box(loc, anc, idx)
                        : make_float4(-1.f, -1.f, -1.f, -1.f);   // sentinel
        if (vmask && val) atomicOr(&vmask[q >> 6], 1ull << (q & 63));
    }
}

// ---------------- K5f: suppression bitmask (fast path) ------------------
__global__ __launch_bounds__(64) void k_supp(const float4* __restrict__ topbox,
                                             ull* __restrict__ supp) {
    int cb = blockIdx.x, rb = blockIdx.y;
    int i = rb * 64 + threadIdx.x;
    if (cb < rb) {                              // strictly lower triangle
        if (i < PRE_NMS) supp[(size_t)i * KW + cb] = 0ull;
        return;
    }
    __shared__ float4 cbox[64];
    int jt = cb * 64 + threadIdx.x;
    cbox[threadIdx.x] = (jt < PRE_NMS) ? topbox[jt] : make_float4(0.f, 0.f, 0.f, 0.f);
    __syncthreads();
    if (i >= PRE_NMS) return;
    float4 bi = topbox[i];
    float ai = (bi.z - bi.x) * (bi.w - bi.y);
    ull bits = 0ull;
    int j0 = cb * 64;
    for (int jj = 0; jj < 64; jj++) {
        int j = j0 + jj;
        if (j <= i || j >= PRE_NMS) continue;
        float4 bj = cbox[jj];
        float aj = (bj.z - bj.x) * (bj.w - bj.y);
        float lx = fmaxf(bi.x, bj.x), ly = fmaxf(bi.y, bj.y);
        float rx = fminf(bi.z, bj.z), ry = fminf(bi.w, bj.w);
        float iw = fmaxf(rx - lx, 0.f), ih = fmaxf(ry - ly, 0.f);
        float inter = iw * ih;
        float iou = inter / (ai + aj - inter + 1e-12f);
        if (iou > IOU_TH) bits |= (1ull << jj);
    }
    supp[(size_t)i * KW + cb] = bits;
}

// ---------------- helpers for serial scans ------------------------------
__device__ inline ull bcast64(ull v, int lane) {
    unsigned lo = (unsigned)v, hi = (unsigned)(v >> 32);
    lo = (unsigned)__shfl((int)lo, lane, 64);
    hi = (unsigned)__shfl((int)hi, lane, 64);
    return ((ull)hi << 32) | lo;
}

// ---------------- K6f: serial bitmask scan, early exit @300 -------------
__global__ __launch_bounds__(64) void k_scan(const ull* __restrict__ supp,
                                             const ull* __restrict__ vmask,
                                             const float4* __restrict__ topbox,
                                             float* __restrict__ out) {
    int l = threadIdx.x;
    ull r0 = 0ull, r1 = 0ull;     // suppressed-bit words l and 64+l
    int nk = 0;
    for (int c = 0; c < KW && nk < POST_NMS; c++) {
        ull cur = (c < 64) ? bcast64(r0, c) : bcast64(r1, c - 64);
        ull todo = ~cur & vmask[c];
        while (todo) {
            int b = __builtin_ctzll(todo);
            todo &= todo - 1ull;
            int i = c * 64 + b;
            const ull* row = supp + (size_t)i * KW;   // issue row load early
            ull w0 = row[l];
            ull w1 = (l < KW - 64) ? row[64 + l] : 0ull;
            float4 bb = topbox[i];
            if (l < 4)
                out[4 * nk + l] = (l == 0) ? bb.x : (l == 1) ? bb.y : (l == 2) ? bb.z : bb.w;
            nk++;
            if (nk == POST_NMS) break;
            r0 |= w0;
            r1 |= w1;
            ull curn = (c < 64) ? bcast64(r0, c) : bcast64(r1, c - 64);
            todo &= ~curn;
        }
    }
    for (int t = nk * 4 + l; t < POST_NMS * 4; t += 64) out[t] = 0.f;
}

// ---------------- K5s: single-wave streaming NMS (small-ws fallback) ----
__global__ __launch_bounds__(64) void k_nms(const float4* __restrict__ topbox,
                                            float* __restrict__ out) {
    int l = threadIdx.x;
    float4 kb[5];
    int nk = 0;
    for (int q0 = 0; q0 < TB_PAD && nk < POST_NMS; q0 += 64) {
        float4 myb = topbox[q0 + l];
        for (int b = 0; b < 64 && nk < POST_NMS; b++) {
            float4 bb;
            bb.x = __shfl(myb.x, b, 64);
            bb.y = __shfl(myb.y, b, 64);
            bb.z = __shfl(myb.z, b, 64);
            bb.w = __shfl(myb.w, b, 64);
            if (bb.x < 0.f) continue;
            float ab = (bb.z - bb.x) * (bb.w - bb.y);
            bool sup = false;
            #pragma unroll
            for (int r = 0; r < 5; r++) {
                int s = r * 64 + l;
                if (s < nk) {
                    float4 kv = kb[r];
                    float ak = (kv.z - kv.x) * (kv.w - kv.y);
                    float lx = fmaxf(bb.x, kv.x), ly = fmaxf(bb.y, kv.y);
                    float rx = fminf(bb.z, kv.z), ry = fminf(bb.w, kv.w);
                    float iw = fmaxf(rx - lx, 0.f), ih = fmaxf(ry - ly, 0.f);
                    float inter = iw * ih;
                    float iou = inter / (ab + ak - inter + 1e-12f);
                    sup |= (iou > IOU_TH);
                }
            }
            if (!__any(sup)) {
                if (l == (nk & 63)) kb[nk >> 6] = bb;
                if (l < 4) {
                    float v = (l == 0) ? bb.x : (l == 1) ? bb.y : (l == 2) ? bb.z : bb.w;
                    out[4 * nk + l] = v;
                }
                nk++;
            }
        }
    }
    for (int t = nk * 4 + l; t < POST_NMS * 4; t += 64) out[t] = 0.f;
}

extern "C" void kernel_launch(void* const* d_in, const int* in_sizes, int n_in,
                              void* d_out, int out_size, void* d_ws, size_t ws_size,
                              hipStream_t stream) {
    const int N = in_sizes[0] / 2;             // 202500
    const float* cls = (const float*)d_in[0];
    const float* loc = (const float*)d_in[1];
    const float* anc = (const float*)d_in[2];
    float* out = (float*)d_out;

    char* ws = (char*)d_ws;
    size_t off = 0;
    auto take = [&](size_t bytes) {
        size_t o = off;
        off += (bytes + 255) & ~(size_t)255;
        return o;
    };
    // base region (~225 KB, validated in R2)
    unsigned* hist = (unsigned*)(ws + take((size_t)NBUCK * 4));      // 64 KB
    char*     mblk = ws + take(1024);                                // meta + vmask
    unsigned* meta  = (unsigned*)mblk;
    ull*      vmask = (ull*)(mblk + 256);                            // 94 words
    ull*    cand   = (ull*)(ws + take((size_t)CAP * 8));             // 64 KB
    float4* topbox = (float4*)(ws + take((size_t)TB_PAD * 16));      // 94 KB
    // fast-path extras
    unsigned* keyc = (unsigned*)(ws + take((size_t)N * 4));          // 810 KB
    ull*      supp = (ull*)(ws + take((size_t)PRE_NMS * KW * 8));    // 4.42 MB
    size_t full_need = off;
    const bool fast = (ws_size >= full_need);   // constant across calls -> graph-safe

    hipMemsetAsync(hist, 0, (size_t)NBUCK * 4, stream);
    hipMemsetAsync(mblk, 0, 1024, stream);

    if (fast) {
        k_score<<<(N + 255) / 256, 256, 0, stream>>>(cls, loc, anc, hist, keyc, N);
        k_findb<<<1, 1024, 0, stream>>>(hist, meta);
        k_compactC<<<(N + 255) / 256, 256, 0, stream>>>(keyc, meta, cand, N);
        k_sort<<<1, 1024, 0, stream>>>(cand, meta, loc, anc, topbox, vmask);
        k_supp<<<dim3(KW, KW), 64, 0, stream>>>(topbox, supp);
        k_scan<<<1, 64, 0, stream>>>(supp, vmask, topbox, out);
    } else {
        k_score<<<(N + 255) / 256, 256, 0, stream>>>(cls, loc, anc, hist, (unsigned*)nullptr, N);
        k_findb<<<1, 1024, 0, stream>>>(hist, meta);
        k_compactR<<<(N + 255) / 256, 256, 0, stream>>>(cls, loc, anc, meta, cand, N);
        k_sort<<<1, 1024, 0, stream>>>(cand, meta, loc, anc, topbox, (ull*)nullptr);
        k_nms<<<1, 64, 0, stream>>>(topbox, out);
    }
}

// Round 4
// 314.545 us; speedup vs baseline: 1.7888x; 1.7888x over previous
//
#include <hip/hip_runtime.h>
#include <hip/hip_bf16.h>

#define NANCH 202500
#define PRE_NMS 6000
#define POST_NMS 300
#define KW 94            // ceil(6016/64) words per supp row
#define CAP 8192
#define NBUCK 16384
#define BSHIFT 18
#define IOU_TH 0.7f
#define MIN_SIZE 0.016f
#define TB_PAD 6016      // topbox padded to a multiple of 64
#define DIAG_ROWS 512
#define DIAG_WORDS 8     // 512 bits
#define RTILE 1024

typedef unsigned long long ull;

// ---------------- shared decode / key helpers ---------------------------
__device__ inline float4 decode_box(const float* __restrict__ loc,
                                    const float* __restrict__ anc, int i) {
    float4 a = ((const float4*)anc)[i];
    float4 t = ((const float4*)loc)[i];
    float pw = a.z - a.x, ph = a.w - a.y;
    float pcx = (a.x + a.z) * 0.5f, pcy = (a.y + a.w) * 0.5f;
    float cx = t.x * pw + pcx, cy = t.y * ph + pcy;
    float w = expf(t.z) * pw, h = expf(t.w) * ph;
    float x1 = fminf(fmaxf(cx - 0.5f * w, 0.f), 1.f);
    float y1 = fminf(fmaxf(cy - 0.5f * h, 0.f), 1.f);
    float x2 = fminf(fmaxf(cx + 0.5f * w, 0.f), 1.f);
    float y2 = fminf(fmaxf(cy + 0.5f * h, 0.f), 1.f);
    return make_float4(x1, y1, x2, y2);
}

__device__ inline unsigned make_key(const float* __restrict__ cls,
                                    const float* __restrict__ loc,
                                    const float* __restrict__ anc, int i) {
    float2 c = ((const float2*)cls)[i];
    float d = c.y - c.x;                       // monotone proxy for softmax[:,1]
    float4 b = decode_box(loc, anc, i);
    bool valid = ((b.z - b.x) >= MIN_SIZE) && ((b.w - b.y) >= MIN_SIZE);
    unsigned ib = __float_as_uint(d);
    unsigned u = (ib & 0x80000000u) ? ~ib : (ib | 0x80000000u);  // monotonic key
    return valid ? u : 0u;                     // invalid -> below everything
}

__device__ inline ull bcast64(ull v, int lane) {
    unsigned lo = (unsigned)v, hi = (unsigned)(v >> 32);
    lo = (unsigned)__shfl((int)lo, lane, 64);
    hi = (unsigned)__shfl((int)hi, lane, 64);
    return ((ull)hi << 32) | lo;
}

// ---------------- K1: histogram (+ optional key cache) -------------------
__global__ __launch_bounds__(256) void k_score(const float* __restrict__ cls,
                                               const float* __restrict__ loc,
                                               const float* __restrict__ anc,
                                               unsigned* __restrict__ hist,
                                               unsigned* __restrict__ keyc, int n) {
    int i = blockIdx.x * blockDim.x + threadIdx.x;
    if (i >= n) return;
    unsigned u = make_key(cls, loc, anc, i);
    if (keyc) keyc[i] = u;
    atomicAdd(&hist[u >> BSHIFT], 1u);
}

// ---------------- K2: find boundary bucket B (rank 6000 from top) -------
__global__ __launch_bounds__(1024) void k_findb(const unsigned* __restrict__ hist,
                                                unsigned* __restrict__ meta) {
    __shared__ unsigned ps[1024];
    int t = threadIdx.x;
    int base = t * (NBUCK / 1024);
    unsigned local = 0;
    for (int b = 0; b < NBUCK / 1024; b++) local += hist[base + b];
    ps[t] = local;
    __syncthreads();
    for (int off = 1; off < 1024; off <<= 1) {
        unsigned add = (t + off < 1024) ? ps[t + off] : 0u;
        __syncthreads();
        ps[t] += add;
        __syncthreads();
    }
    unsigned incl = ps[t];
    unsigned excl = incl - local;
    if (incl >= (unsigned)PRE_NMS && excl < (unsigned)PRE_NMS) {
        unsigned cum = excl;
        int B = base;
        for (int b = NBUCK / 1024 - 1; b >= 0; b--) {
            cum += hist[base + b];
            if (cum >= (unsigned)PRE_NMS) { B = base + b; break; }
        }
        meta[0] = (unsigned)B;
    }
}

// ---------------- K3a: compact (cached keys, wave-aggregated atomic) ----
__global__ __launch_bounds__(256) void k_compactC(const unsigned* __restrict__ keyc,
                                                  unsigned* __restrict__ meta,
                                                  ull* __restrict__ cand, int n) {
    int i = blockIdx.x * blockDim.x + threadIdx.x;
    unsigned u = (i < n) ? keyc[i] : 0u;
    unsigned B = meta[0];
    bool pred = (i < n) && ((u >> BSHIFT) >= B);
    ull mask = __ballot(pred);
    if (!mask) return;
    int lane = threadIdx.x & 63;
    int leader = __builtin_ctzll(mask);
    unsigned base = 0;
    if (lane == leader) base = atomicAdd(&meta[1], (unsigned)__popcll(mask));
    base = (unsigned)__shfl((int)base, leader, 64);
    if (pred) {
        unsigned p = base + (unsigned)__popcll(mask & ((1ull << lane) - 1ull));
        if (p < CAP) cand[p] = ((ull)(~u) << 32) | (unsigned)i;
    }
}

// ---------------- K3b: compact, recompute keys (small-ws fallback) ------
__global__ __launch_bounds__(256) void k_compactR(const float* __restrict__ cls,
                                                  const float* __restrict__ loc,
                                                  const float* __restrict__ anc,
                                                  unsigned* __restrict__ meta,
                                                  ull* __restrict__ cand, int n) {
    int i = blockIdx.x * blockDim.x + threadIdx.x;
    if (i >= n) return;
    unsigned u = make_key(cls, loc, anc, i);
    if ((u >> BSHIFT) >= meta[0]) {
        unsigned p = atomicAdd(&meta[1], 1u);
        if (p < CAP) cand[p] = ((ull)(~u) << 32) | (unsigned)i;
    }
}

// ---------------- K4a: exact rank by counting (replaces bitonic sort) ---
// Keys are unique (anchor idx embedded), so rank = #{j: key_j < key_i} is an
// exact permutation of [0,C). 67M u64 compares over 256 blocks, LDS-tiled.
__global__ __launch_bounds__(256) void k_rank(const ull* __restrict__ cand,
                                              const unsigned* __restrict__ meta,
                                              unsigned* __restrict__ rank,
                                              float4* __restrict__ topbox) {
    __shared__ __align__(16) ull tile[RTILE];
    int tid = threadIdx.x;
    int bx = blockIdx.x, by = blockIdx.y;
    unsigned C = meta[1]; if (C > CAP) C = CAP;
    if (by == 0 && tid < TB_PAD / 32) {        // prefill sentinel (runs before scatter)
        int q = bx * (TB_PAD / 32) + tid;
        topbox[q] = make_float4(-1.f, -1.f, -1.f, -1.f);
    }
    int i = bx * 256 + tid;
    ull ki = (i < (int)C) ? cand[i] : ~0ull;
    int j0 = by * RTILE;
    for (int q = tid; q < RTILE; q += 256) {
        int j = j0 + q;
        tile[q] = (j < (int)C) ? cand[j] : ~0ull; // pad = +inf (never < real key)
    }
    __syncthreads();
    const ulonglong2* t2 = (const ulonglong2*)tile;
    unsigned cnt = 0;
    for (int q = 0; q < RTILE / 2; q++) {
        ulonglong2 v = t2[q];
        cnt += (v.x < ki) + (v.y < ki);
    }
    if (cnt) atomicAdd(&rank[i], cnt);
}

// ---------------- K4b: scatter + decode to rank position ----------------
__global__ __launch_bounds__(256) void k_scatter(const ull* __restrict__ cand,
                                                 const unsigned* __restrict__ meta,
                                                 const unsigned* __restrict__ rank,
                                                 const float* __restrict__ loc,
                                                 const float* __restrict__ anc,
                                                 float4* __restrict__ topbox,
                                                 ull* __restrict__ vmask) {
    int i = blockIdx.x * 256 + threadIdx.x;
    unsigned C = meta[1]; if (C > CAP) C = CAP;
    if (i >= (int)C) return;
    ull kv = cand[i];
    unsigned uu = ~(unsigned)(kv >> 32);
    if (uu == 0u) return;                      // invalid box -> slot stays sentinel
    unsigned r = rank[i];
    if (r >= PRE_NMS) return;                  // outside top-6000
    int idx = (int)(unsigned)kv;
    topbox[r] = decode_box(loc, anc, idx);
    atomicOr(&vmask[r >> 6], 1ull << (r & 63));
}

// ---------------- K5: suppression bitmask --------------------------------
__global__ __launch_bounds__(64) void k_supp(const float4* __restrict__ topbox,
                                             ull* __restrict__ supp) {
    int cb = blockIdx.x, rb = blockIdx.y;
    int i = rb * 64 + threadIdx.x;
    if (cb < rb) {                              // strictly lower triangle
        if (i < PRE_NMS) supp[(size_t)i * KW + cb] = 0ull;
        return;
    }
    __shared__ float4 cbox[64];
    int jt = cb * 64 + threadIdx.x;
    cbox[threadIdx.x] = (jt < PRE_NMS) ? topbox[jt] : make_float4(0.f, 0.f, 0.f, 0.f);
    __syncthreads();
    if (i >= PRE_NMS) return;
    float4 bi = topbox[i];
    float ai = (bi.z - bi.x) * (bi.w - bi.y);
    ull bits = 0ull;
    int j0 = cb * 64;
    for (int jj = 0; jj < 64; jj++) {
        int j = j0 + jj;
        if (j <= i || j >= PRE_NMS) continue;
        float4 bj = cbox[jj];
        float aj = (bj.z - bj.x) * (bj.w - bj.y);
        float lx = fmaxf(bi.x, bj.x), ly = fmaxf(bi.y, bj.y);
        float rx = fminf(bi.z, bj.z), ry = fminf(bi.w, bj.w);
        float iw = fmaxf(rx - lx, 0.f), ih = fmaxf(ry - ly, 0.f);
        float inter = iw * ih;
        float iou = inter / (ai + aj - inter + 1e-12f);
        if (iou > IOU_TH) bits |= (1ull << jj);
    }
    supp[(size_t)i * KW + cb] = bits;
}

// ---------------- K6: serial scan — LDS diag tile + rare global phase B -
__global__ __launch_bounds__(64) void k_scan(const ull* __restrict__ supp,
                                             const ull* __restrict__ vmask,
                                             const float4* __restrict__ topbox,
                                             float* __restrict__ out) {
    __shared__ ull ds[DIAG_ROWS * DIAG_WORDS];   // 32 KB: rows 0..511, words 0..7
    __shared__ int klist[POST_NMS];
    int l = threadIdx.x;
    for (int q = l; q < DIAG_ROWS * DIAG_WORDS; q += 64) {
        int r = q >> 3, w = q & 7;
        ds[q] = supp[(size_t)r * KW + w];
    }
    // single wave -> LDS ops complete in issue order, no barrier needed
    int nk = 0;
    ull rA = 0ull;                              // word l of 512-bit state (lanes 0..7)
    bool done = false;
    for (int c = 0; c < DIAG_WORDS && !done; c++) {
        ull todo = ~bcast64(rA, c) & vmask[c];
        while (todo) {
            int b = __builtin_ctzll(todo);
            todo &= todo - 1ull;
            int i = c * 64 + b;
            ull w = (l < DIAG_WORDS) ? ds[i * DIAG_WORDS + l] : 0ull;
            if (l == 0) klist[nk] = i;
            nk++;
            if (nk == POST_NMS) { done = true; break; }
            rA |= w;
            todo &= ~bcast64(w, c);             // bits newly suppressed by box i
        }
    }
    if (!done) {                                // ---- phase B (rare) ----
        ull r0 = 0ull, r1 = 0ull;
        for (int q = 0; q < nk; q++) {          // rebuild full 6016-bit state
            const ull* row = supp + (size_t)klist[q] * KW;
            r0 |= row[l];
            if (l < KW - 64) r1 |= row[64 + l];
        }
        for (int c = DIAG_WORDS; c < KW && !done; c++) {
            ull cur = (c < 64) ? bcast64(r0, c) : bcast64(r1, c - 64);
            ull todo = ~cur & vmask[c];
            while (todo) {
                int b = __builtin_ctzll(todo);
                todo &= todo - 1ull;
                int i = c * 64 + b;
                const ull* row = supp + (size_t)i * KW;
                ull w0 = row[l];
                ull w1 = (l < KW - 64) ? row[64 + l] : 0ull;
                if (l == 0) klist[nk] = i;
                nk++;
                if (nk == POST_NMS) { done = true; break; }
                r0 |= w0; r1 |= w1;
                ull curn = (c < 64) ? bcast64(r0, c) : bcast64(r1, c - 64);
                todo &= ~curn;
            }
        }
    }
    for (int q = l; q < nk; q += 64)            // batched output, off critical path
        ((float4*)out)[q] = topbox[klist[q]];
    for (int q = nk + l; q < POST_NMS; q += 64)
        ((float4*)out)[q] = make_float4(0.f, 0.f, 0.f, 0.f);
}

// ---------------- K5s: single-wave streaming NMS (small-ws fallback) ----
__global__ __launch_bounds__(64) void k_nms(const float4* __restrict__ topbox,
                                            float* __restrict__ out) {
    int l = threadIdx.x;
    float4 kb[5];
    int nk = 0;
    for (int q0 = 0; q0 < TB_PAD && nk < POST_NMS; q0 += 64) {
        float4 myb = topbox[q0 + l];
        for (int b = 0; b < 64 && nk < POST_NMS; b++) {
            float4 bb;
            bb.x = __shfl(myb.x, b, 64);
            bb.y = __shfl(myb.y, b, 64);
            bb.z = __shfl(myb.z, b, 64);
            bb.w = __shfl(myb.w, b, 64);
            if (bb.x < 0.f) continue;
            float ab = (bb.z - bb.x) * (bb.w - bb.y);
            bool sup = false;
            #pragma unroll
            for (int r = 0; r < 5; r++) {
                int s = r * 64 + l;
                if (s < nk) {
                    float4 kv = kb[r];
                    float ak = (kv.z - kv.x) * (kv.w - kv.y);
                    float lx = fmaxf(bb.x, kv.x), ly = fmaxf(bb.y, kv.y);
                    float rx = fminf(bb.z, kv.z), ry = fminf(bb.w, kv.w);
                    float iw = fmaxf(rx - lx, 0.f), ih = fmaxf(ry - ly, 0.f);
                    float inter = iw * ih;
                    float iou = inter / (ab + ak - inter + 1e-12f);
                    sup |= (iou > IOU_TH);
                }
            }
            if (!__any(sup)) {
                if (l == (nk & 63)) kb[nk >> 6] = bb;
                if (l < 4) {
                    float v = (l == 0) ? bb.x : (l == 1) ? bb.y : (l == 2) ? bb.z : bb.w;
                    out[4 * nk + l] = v;
                }
                nk++;
            }
        }
    }
    for (int t = nk * 4 + l; t < POST_NMS * 4; t += 64) out[t] = 0.f;
}

extern "C" void kernel_launch(void* const* d_in, const int* in_sizes, int n_in,
                              void* d_out, int out_size, void* d_ws, size_t ws_size,
                              hipStream_t stream) {
    const int N = in_sizes[0] / 2;             // 202500
    const float* cls = (const float*)d_in[0];
    const float* loc = (const float*)d_in[1];
    const float* anc = (const float*)d_in[2];
    float* out = (float*)d_out;

    char* ws = (char*)d_ws;
    size_t off = 0;
    auto take = [&](size_t bytes) {
        size_t o = off;
        off += (bytes + 255) & ~(size_t)255;
        return o;
    };
    // zero-init region: hist + meta/vmask + rank, contiguous -> one memset
    unsigned* hist = (unsigned*)(ws + take((size_t)NBUCK * 4));      // 64 KB
    char*     mblk = ws + take(1024);
    unsigned* meta  = (unsigned*)mblk;
    ull*      vmask = (ull*)(mblk + 256);                            // 94 words
    unsigned* rank = (unsigned*)(ws + take((size_t)CAP * 4));        // 32 KB
    size_t zlen = off;
    // rest
    ull*    cand   = (ull*)(ws + take((size_t)CAP * 8));             // 64 KB
    float4* topbox = (float4*)(ws + take((size_t)TB_PAD * 16));      // 94 KB
    // fast-path extras
    unsigned* keyc = (unsigned*)(ws + take((size_t)N * 4));          // 810 KB
    ull*      supp = (ull*)(ws + take((size_t)PRE_NMS * KW * 8));    // 4.42 MB
    size_t full_need = off;
    const bool fast = (ws_size >= full_need);   // constant across calls -> graph-safe

    hipMemsetAsync(ws, 0, zlen, stream);

    if (fast) {
        k_score<<<(N + 255) / 256, 256, 0, stream>>>(cls, loc, anc, hist, keyc, N);
        k_findb<<<1, 1024, 0, stream>>>(hist, meta);
        k_compactC<<<(N + 255) / 256, 256, 0, stream>>>(keyc, meta, cand, N);
        k_rank<<<dim3(CAP / 256, CAP / RTILE), 256, 0, stream>>>(cand, meta, rank, topbox);
        k_scatter<<<CAP / 256, 256, 0, stream>>>(cand, meta, rank, loc, anc, topbox, vmask);
        k_supp<<<dim3(KW, KW), 64, 0, stream>>>(topbox, supp);
        k_scan<<<1, 64, 0, stream>>>(supp, vmask, topbox, out);
    } else {
        k_score<<<(N + 255) / 256, 256, 0, stream>>>(cls, loc, anc, hist, (unsigned*)nullptr, N);
        k_findb<<<1, 1024, 0, stream>>>(hist, meta);
        k_compactR<<<(N + 255) / 256, 256, 0, stream>>>(cls, loc, anc, meta, cand, N);
        k_rank<<<dim3(CAP / 256, CAP / RTILE), 256, 0, stream>>>(cand, meta, rank, topbox);
        k_scatter<<<CAP / 256, 256, 0, stream>>>(cand, meta, rank, loc, anc, topbox, vmask);
        k_nms<<<1, 64, 0, stream>>>(topbox, out);
    }
}

// Round 5
// 226.964 us; speedup vs baseline: 2.4791x; 1.3859x over previous
//
#include <hip/hip_runtime.h>
#include <hip/hip_bf16.h>

#define NANCH 202500
#define PRE_NMS 6000
#define POST_NMS 300
#define KW 94            // ceil(6016/64) words per supp row
#define CAP 8192
#define NBUCK 16384
#define BSHIFT 18
#define IOU_TH 0.7f
#define MIN_SIZE 0.016f
#define TB_PAD 6016      // topbox padded to a multiple of 64
#define DIAG_ROWS 512
#define DIAG_WORDS 8     // 512 bits
#define RTILE 256        // rank j-tile (small: spread LDS load over many CUs)
#define RITEMS 8         // candidates ranked per thread (register-blocked)
#define SBLK 256         // k_score grid blocks

typedef unsigned long long ull;

// ---------------- shared decode / key helpers ---------------------------
__device__ inline float4 decode_box(const float* __restrict__ loc,
                                    const float* __restrict__ anc, int i) {
    float4 a = ((const float4*)anc)[i];
    float4 t = ((const float4*)loc)[i];
    float pw = a.z - a.x, ph = a.w - a.y;
    float pcx = (a.x + a.z) * 0.5f, pcy = (a.y + a.w) * 0.5f;
    float cx = t.x * pw + pcx, cy = t.y * ph + pcy;
    float w = expf(t.z) * pw, h = expf(t.w) * ph;
    float x1 = fminf(fmaxf(cx - 0.5f * w, 0.f), 1.f);
    float y1 = fminf(fmaxf(cy - 0.5f * h, 0.f), 1.f);
    float x2 = fminf(fmaxf(cx + 0.5f * w, 0.f), 1.f);
    float y2 = fminf(fmaxf(cy + 0.5f * h, 0.f), 1.f);
    return make_float4(x1, y1, x2, y2);
}

__device__ inline unsigned make_key(const float* __restrict__ cls,
                                    const float* __restrict__ loc,
                                    const float* __restrict__ anc, int i) {
    float2 c = ((const float2*)cls)[i];
    float d = c.y - c.x;                       // monotone proxy for softmax[:,1]
    float4 b = decode_box(loc, anc, i);
    bool valid = ((b.z - b.x) >= MIN_SIZE) && ((b.w - b.y) >= MIN_SIZE);
    unsigned ib = __float_as_uint(d);
    unsigned u = (ib & 0x80000000u) ? ~ib : (ib | 0x80000000u);  // monotonic key
    return valid ? u : 0u;                     // invalid -> below everything
}

__device__ inline ull bcast64(ull v, int lane) {
    unsigned lo = (unsigned)v, hi = (unsigned)(v >> 32);
    lo = (unsigned)__shfl((int)lo, lane, 64);
    hi = (unsigned)__shfl((int)hi, lane, 64);
    return ((ull)hi << 32) | lo;
}

// ---------------- K1: keys + per-block LDS histogram ---------------------
// R4 postmortem: global atomic hist had a ~3000-deep hot bucket (d~N(0,1.4)
// crams mass into few float-prefix buckets) -> ~100us of serialized atomics.
// LDS hist absorbs contention; flush adds <=SBLK per bucket, staggered so
// concurrent blocks flush disjoint bucket ranges.
__global__ __launch_bounds__(256) void k_score(const float* __restrict__ cls,
                                               const float* __restrict__ loc,
                                               const float* __restrict__ anc,
                                               unsigned* __restrict__ hist,
                                               unsigned* __restrict__ keyc, int n) {
    __shared__ unsigned lh[NBUCK];             // 64 KB
    int tid = threadIdx.x, bid = blockIdx.x;
    for (int q = tid; q < NBUCK; q += 256) lh[q] = 0u;
    __syncthreads();
    for (int i = bid * 256 + tid; i < n; i += SBLK * 256) {
        unsigned u = make_key(cls, loc, anc, i);
        if (keyc) keyc[i] = u;
        atomicAdd(&lh[u >> BSHIFT], 1u);
    }
    __syncthreads();
    for (int qq = 0; qq < NBUCK / 256; qq++) {
        int q = (qq + bid) & (NBUCK / 256 - 1);     // stagger across blocks
        int b = q * 256 + tid;
        unsigned v = lh[b];
        if (v) atomicAdd(&hist[b], v);
    }
}

// ---------------- K2: find boundary bucket B (rank 6000 from top) -------
__global__ __launch_bounds__(1024) void k_findb(const unsigned* __restrict__ hist,
                                                unsigned* __restrict__ meta) {
    __shared__ unsigned ps[1024];
    int t = threadIdx.x;
    int base = t * (NBUCK / 1024);
    unsigned local = 0;
    for (int b = 0; b < NBUCK / 1024; b++) local += hist[base + b];
    ps[t] = local;
    __syncthreads();
    for (int off = 1; off < 1024; off <<= 1) {
        unsigned add = (t + off < 1024) ? ps[t + off] : 0u;
        __syncthreads();
        ps[t] += add;
        __syncthreads();
    }
    unsigned incl = ps[t];
    unsigned excl = incl - local;
    if (incl >= (unsigned)PRE_NMS && excl < (unsigned)PRE_NMS) {
        unsigned cum = excl;
        int B = base;
        for (int b = NBUCK / 1024 - 1; b >= 0; b--) {
            cum += hist[base + b];
            if (cum >= (unsigned)PRE_NMS) { B = base + b; break; }
        }
        meta[0] = (unsigned)B;
    }
}

// ---------------- K3a: compact (cached keys, wave-aggregated atomic) ----
__global__ __launch_bounds__(256) void k_compactC(const unsigned* __restrict__ keyc,
                                                  unsigned* __restrict__ meta,
                                                  ull* __restrict__ cand, int n) {
    int i = blockIdx.x * blockDim.x + threadIdx.x;
    unsigned u = (i < n) ? keyc[i] : 0u;
    unsigned B = meta[0];
    bool pred = (i < n) && ((u >> BSHIFT) >= B);
    ull mask = __ballot(pred);
    if (!mask) return;
    int lane = threadIdx.x & 63;
    int leader = __builtin_ctzll(mask);
    unsigned base = 0;
    if (lane == leader) base = atomicAdd(&meta[1], (unsigned)__popcll(mask));
    base = (unsigned)__shfl((int)base, leader, 64);
    if (pred) {
        unsigned p = base + (unsigned)__popcll(mask & ((1ull << lane) - 1ull));
        if (p < CAP) cand[p] = ((ull)(~u) << 32) | (unsigned)i;
    }
}

// ---------------- K3b: compact, recompute keys (small-ws fallback) ------
__global__ __launch_bounds__(256) void k_compactR(const float* __restrict__ cls,
                                                  const float* __restrict__ loc,
                                                  const float* __restrict__ anc,
                                                  unsigned* __restrict__ meta,
                                                  ull* __restrict__ cand, int n) {
    int i = blockIdx.x * blockDim.x + threadIdx.x;
    if (i >= n) return;
    unsigned u = make_key(cls, loc, anc, i);
    if ((u >> BSHIFT) >= meta[0]) {
        unsigned p = atomicAdd(&meta[1], 1u);
        if (p < CAP) cand[p] = ((ull)(~u) << 32) | (unsigned)i;
    }
}

// ---------------- K4a: exact rank by counting (register-blocked) --------
// rank[i] = #{j: key_j < key_i}; keys unique -> exact permutation.
// RITEMS candidates/thread: LDS tile broadcast amortized 8x vs R4.
__global__ __launch_bounds__(256) void k_rank(const ull* __restrict__ cand,
                                              const unsigned* __restrict__ meta,
                                              unsigned* __restrict__ rank,
                                              float4* __restrict__ topbox) {
    __shared__ __align__(16) ull tile[RTILE];  // 2 KB
    int tid = threadIdx.x;
    int bx = blockIdx.x, by = blockIdx.y;
    unsigned C = meta[1]; if (C > CAP) C = CAP;
    if (by == 0) {                             // sentinel prefill (before scatter)
        int per = TB_PAD / (CAP / (256 * RITEMS));    // 6016/4 = 1504
        int s0 = bx * per;
        for (int q = tid; q < per; q += 256)
            topbox[s0 + q] = make_float4(-1.f, -1.f, -1.f, -1.f);
    }
    int ibase = bx * 256 * RITEMS;
    ull ki[RITEMS]; unsigned cnt[RITEMS];
    #pragma unroll
    for (int r = 0; r < RITEMS; r++) {
        int i = ibase + r * 256 + tid;
        ki[r] = (i < (int)C) ? cand[i] : ~0ull;
        cnt[r] = 0u;
    }
    int j = by * RTILE + tid;
    tile[tid] = (j < (int)C) ? cand[j] : ~0ull;   // pad = +inf (never < real key)
    __syncthreads();
    const ulonglong2* t2 = (const ulonglong2*)tile;
    for (int q = 0; q < RTILE / 2; q++) {
        ulonglong2 v = t2[q];
        #pragma unroll
        for (int r = 0; r < RITEMS; r++)
            cnt[r] += (unsigned)(v.x < ki[r]) + (unsigned)(v.y < ki[r]);
    }
    #pragma unroll
    for (int r = 0; r < RITEMS; r++)
        if (cnt[r]) atomicAdd(&rank[ibase + r * 256 + tid], cnt[r]);
}

// ---------------- K4b: scatter + decode to rank position ----------------
__global__ __launch_bounds__(256) void k_scatter(const ull* __restrict__ cand,
                                                 const unsigned* __restrict__ meta,
                                                 const unsigned* __restrict__ rank,
                                                 const float* __restrict__ loc,
                                                 const float* __restrict__ anc,
                                                 float4* __restrict__ topbox,
                                                 ull* __restrict__ vmask) {
    int i = blockIdx.x * 256 + threadIdx.x;
    unsigned C = meta[1]; if (C > CAP) C = CAP;
    if (i >= (int)C) return;
    ull kv = cand[i];
    unsigned uu = ~(unsigned)(kv >> 32);
    if (uu == 0u) return;                      // invalid box -> slot stays sentinel
    unsigned r = rank[i];
    if (r >= PRE_NMS) return;                  // outside top-6000
    int idx = (int)(unsigned)kv;
    topbox[r] = decode_box(loc, anc, idx);
    atomicOr(&vmask[r >> 6], 1ull << (r & 63));
}

// ---------------- K5: suppression bitmask --------------------------------
__global__ __launch_bounds__(64) void k_supp(const float4* __restrict__ topbox,
                                             ull* __restrict__ supp) {
    int cb = blockIdx.x, rb = blockIdx.y;
    int i = rb * 64 + threadIdx.x;
    if (cb < rb) {                              // strictly lower triangle
        if (i < PRE_NMS) supp[(size_t)i * KW + cb] = 0ull;
        return;
    }
    __shared__ float4 cbox[64];
    int jt = cb * 64 + threadIdx.x;
    cbox[threadIdx.x] = (jt < PRE_NMS) ? topbox[jt] : make_float4(0.f, 0.f, 0.f, 0.f);
    __syncthreads();
    if (i >= PRE_NMS) return;
    float4 bi = topbox[i];
    float ai = (bi.z - bi.x) * (bi.w - bi.y);
    ull bits = 0ull;
    int j0 = cb * 64;
    for (int jj = 0; jj < 64; jj++) {
        int j = j0 + jj;
        if (j <= i || j >= PRE_NMS) continue;
        float4 bj = cbox[jj];
        float aj = (bj.z - bj.x) * (bj.w - bj.y);
        float lx = fmaxf(bi.x, bj.x), ly = fmaxf(bi.y, bj.y);
        float rx = fminf(bi.z, bj.z), ry = fminf(bi.w, bj.w);
        float iw = fmaxf(rx - lx, 0.f), ih = fmaxf(ry - ly, 0.f);
        float inter = iw * ih;
        float iou = inter / (ai + aj - inter + 1e-12f);
        if (iou > IOU_TH) bits |= (1ull << jj);
    }
    supp[(size_t)i * KW + cb] = bits;
}

// ---------------- K6: serial scan — LDS diag tile + rare global phase B -
__global__ __launch_bounds__(64) void k_scan(const ull* __restrict__ supp,
                                             const ull* __restrict__ vmask,
                                             const float4* __restrict__ topbox,
                                             float* __restrict__ out) {
    __shared__ ull ds[DIAG_ROWS * DIAG_WORDS];   // 32 KB
    __shared__ int klist[POST_NMS];
    int l = threadIdx.x;
    for (int q = l; q < DIAG_ROWS * DIAG_WORDS; q += 64) {
        int r = q >> 3, w = q & 7;
        ds[q] = supp[(size_t)r * KW + w];
    }
    int nk = 0;
    ull rA = 0ull;
    bool done = false;
    for (int c = 0; c < DIAG_WORDS && !done; c++) {
        ull todo = ~bcast64(rA, c) & vmask[c];
        while (todo) {
            int b = __builtin_ctzll(todo);
            todo &= todo - 1ull;
            int i = c * 64 + b;
            ull w = (l < DIAG_WORDS) ? ds[i * DIAG_WORDS + l] : 0ull;
            if (l == 0) klist[nk] = i;
            nk++;
            if (nk == POST_NMS) { done = true; break; }
            rA |= w;
            todo &= ~bcast64(w, c);
        }
    }
    if (!done) {                                // ---- phase B (rare) ----
        ull r0 = 0ull, r1 = 0ull;
        for (int q = 0; q < nk; q++) {
            const ull* row = supp + (size_t)klist[q] * KW;
            r0 |= row[l];
            if (l < KW - 64) r1 |= row[64 + l];
        }
        for (int c = DIAG_WORDS; c < KW && !done; c++) {
            ull cur = (c < 64) ? bcast64(r0, c) : bcast64(r1, c - 64);
            ull todo = ~cur & vmask[c];
            while (todo) {
                int b = __builtin_ctzll(todo);
                todo &= todo - 1ull;
                int i = c * 64 + b;
                const ull* row = supp + (size_t)i * KW;
                ull w0 = row[l];
                ull w1 = (l < KW - 64) ? row[64 + l] : 0ull;
                if (l == 0) klist[nk] = i;
                nk++;
                if (nk == POST_NMS) { done = true; break; }
                r0 |= w0; r1 |= w1;
                ull curn = (c < 64) ? bcast64(r0, c) : bcast64(r1, c - 64);
                todo &= ~curn;
            }
        }
    }
    for (int q = l; q < nk; q += 64)
        ((float4*)out)[q] = topbox[klist[q]];
    for (int q = nk + l; q < POST_NMS; q += 64)
        ((float4*)out)[q] = make_float4(0.f, 0.f, 0.f, 0.f);
}

// ---------------- K5s: single-wave streaming NMS (small-ws fallback) ----
__global__ __launch_bounds__(64) void k_nms(const float4* __restrict__ topbox,
                                            float* __restrict__ out) {
    int l = threadIdx.x;
    float4 kb[5];
    int nk = 0;
    for (int q0 = 0; q0 < TB_PAD && nk < POST_NMS; q0 += 64) {
        float4 myb = topbox[q0 + l];
        for (int b = 0; b < 64 && nk < POST_NMS; b++) {
            float4 bb;
            bb.x = __shfl(myb.x, b, 64);
            bb.y = __shfl(myb.y, b, 64);
            bb.z = __shfl(myb.z, b, 64);
            bb.w = __shfl(myb.w, b, 64);
            if (bb.x < 0.f) continue;
            float ab = (bb.z - bb.x) * (bb.w - bb.y);
            bool sup = false;
            #pragma unroll
            for (int r = 0; r < 5; r++) {
                int s = r * 64 + l;
                if (s < nk) {
                    float4 kv = kb[r];
                    float ak = (kv.z - kv.x) * (kv.w - kv.y);
                    float lx = fmaxf(bb.x, kv.x), ly = fmaxf(bb.y, kv.y);
                    float rx = fminf(bb.z, kv.z), ry = fminf(bb.w, kv.w);
                    float iw = fmaxf(rx - lx, 0.f), ih = fmaxf(ry - ly, 0.f);
                    float inter = iw * ih;
                    float iou = inter / (ab + ak - inter + 1e-12f);
                    sup |= (iou > IOU_TH);
                }
            }
            if (!__any(sup)) {
                if (l == (nk & 63)) kb[nk >> 6] = bb;
                if (l < 4) {
                    float v = (l == 0) ? bb.x : (l == 1) ? bb.y : (l == 2) ? bb.z : bb.w;
                    out[4 * nk + l] = v;
                }
                nk++;
            }
        }
    }
    for (int t = nk * 4 + l; t < POST_NMS * 4; t += 64) out[t] = 0.f;
}

extern "C" void kernel_launch(void* const* d_in, const int* in_sizes, int n_in,
                              void* d_out, int out_size, void* d_ws, size_t ws_size,
                              hipStream_t stream) {
    const int N = in_sizes[0] / 2;             // 202500
    const float* cls = (const float*)d_in[0];
    const float* loc = (const float*)d_in[1];
    const float* anc = (const float*)d_in[2];
    float* out = (float*)d_out;

    char* ws = (char*)d_ws;
    size_t off = 0;
    auto take = [&](size_t bytes) {
        size_t o = off;
        off += (bytes + 255) & ~(size_t)255;
        return o;
    };
    // zero-init region: hist + meta/vmask + rank, contiguous -> one memset
    unsigned* hist = (unsigned*)(ws + take((size_t)NBUCK * 4));      // 64 KB
    char*     mblk = ws + take(1024);
    unsigned* meta  = (unsigned*)mblk;
    ull*      vmask = (ull*)(mblk + 256);                            // 94 words
    unsigned* rank = (unsigned*)(ws + take((size_t)CAP * 4));        // 32 KB
    size_t zlen = off;
    // rest
    ull*    cand   = (ull*)(ws + take((size_t)CAP * 8));             // 64 KB
    float4* topbox = (float4*)(ws + take((size_t)TB_PAD * 16));      // 94 KB
    // fast-path extras
    unsigned* keyc = (unsigned*)(ws + take((size_t)N * 4));          // 810 KB
    ull*      supp = (ull*)(ws + take((size_t)PRE_NMS * KW * 8));    // 4.42 MB
    size_t full_need = off;
    const bool fast = (ws_size >= full_need);   // constant across calls -> graph-safe

    hipMemsetAsync(ws, 0, zlen, stream);

    dim3 rgrid(CAP / (256 * RITEMS), CAP / RTILE);   // (4, 32)

    if (fast) {
        k_score<<<SBLK, 256, 0, stream>>>(cls, loc, anc, hist, keyc, N);
        k_findb<<<1, 1024, 0, stream>>>(hist, meta);
        k_compactC<<<(N + 255) / 256, 256, 0, stream>>>(keyc, meta, cand, N);
        k_rank<<<rgrid, 256, 0, stream>>>(cand, meta, rank, topbox);
        k_scatter<<<CAP / 256, 256, 0, stream>>>(cand, meta, rank, loc, anc, topbox, vmask);
        k_supp<<<dim3(KW, KW), 64, 0, stream>>>(topbox, supp);
        k_scan<<<1, 64, 0, stream>>>(supp, vmask, topbox, out);
    } else {
        k_score<<<SBLK, 256, 0, stream>>>(cls, loc, anc, hist, (unsigned*)nullptr, N);
        k_findb<<<1, 1024, 0, stream>>>(hist, meta);
        k_compactR<<<(N + 255) / 256, 256, 0, stream>>>(cls, loc, anc, meta, cand, N);
        k_rank<<<rgrid, 256, 0, stream>>>(cand, meta, rank, topbox);
        k_scatter<<<CAP / 256, 256, 0, stream>>>(cand, meta, rank, loc, anc, topbox, vmask);
        k_nms<<<1, 64, 0, stream>>>(topbox, out);
    }
}